// Round 6
// baseline (245.470 us; speedup 1.0000x reference)
//
#include <hip/hip_runtime.h>

#define TPB  256
#define NBLK 2048

// y is exactly 0.0f or 1.0f; -(y*log(p) + (1-y)*log1p(-p)) reduces to a select.
__device__ __forceinline__ float bce1(float p, float y) {
    return (y > 0.5f) ? -__logf(p) : -__logf(1.0f - p);
}
__device__ __forceinline__ float bce4(float4 p, float4 y) {
    return bce1(p.x, y.x) + bce1(p.y, y.y) + bce1(p.z, y.z) + bce1(p.w, y.w);
}

__global__ void __launch_bounds__(TPB) hml_fused(
    const float* __restrict__ l1p, const float* __restrict__ l2pCC,
    const float* __restrict__ l2pURW,
    const float* __restrict__ p3a, const float* __restrict__ p3b,
    const float* __restrict__ p3c, const float* __restrict__ p3d,
    const float* __restrict__ p3e,
    const float* __restrict__ l1y, const float* __restrict__ l2yCC,
    const float* __restrict__ l2yURW,
    const float* __restrict__ y3a, const float* __restrict__ y3b,
    const float* __restrict__ y3c, const float* __restrict__ y3d,
    const float* __restrict__ y3e,
    int nrows, double* __restrict__ acc, unsigned int* __restrict__ done,
    float* __restrict__ out)
{
    double s1 = 0, s2cc = 0, s2urw = 0, s3 = 0, nCC = 0, nURW = 0, n3 = 0;
    const int  tid = blockIdx.x * blockDim.x + threadIdx.x;
    const long T   = (long)gridDim.x * blockDim.x;

    // ---------- phase A: level1 + level2 + n3 count (per row) ----------
    for (long i = tid; i < nrows; i += T) {
        float2 p1 = ((const float2*)l1p)[i];
        float2 y1 = ((const float2*)l1y)[i];
        float2 pu = ((const float2*)l2pURW)[i];
        float2 yu = ((const float2*)l2yURW)[i];
        float c0p = l2pCC[i*3+0], c1p = l2pCC[i*3+1], c2p = l2pCC[i*3+2];
        float c0y = l2yCC[i*3+0], c1y = l2yCC[i*3+1], c2y = l2yCC[i*3+2];

        s1 += (double)(bce1(p1.x, y1.x) + bce1(p1.y, y1.y));

        const bool aCC  = (y1.x > 0.5f);
        const bool aURW = (y1.y > 0.5f);
        const float fCC  = aCC  ? 1.f : 0.f;
        const float fURW = aURW ? 1.f : 0.f;

        s2cc  += (double)(fCC  * (bce1(c0p, c0y) + bce1(c1p, c1y) + bce1(c2p, c2y)));
        s2urw += (double)(fURW * (bce1(pu.x, yu.x) + bce1(pu.y, yu.y)));
        nCC   += (double)fCC;
        nURW  += (double)fURW;

        n3 += (double)(((aCC  && c0y  != 0.f) ? 1 : 0) +
                       ((aCC  && c1y  != 0.f) ? 1 : 0) +
                       ((aCC  && c2y  != 0.f) ? 1 : 0) +
                       ((aURW && yu.x != 0.f) ? 1 : 0) +
                       ((aURW && yu.y != 0.f) ? 1 : 0));
    }

    // ---------- phase B: level3 — ONE array-pair at a time (round-3 structure) ----
    // Sequential contiguous streaming per entry: no cross-array aliasing (the
    // 10 arrays are 32MiB-congruent; simultaneous same-index loads to several
    // arrays hit the same L2 sets / HBM channels — measured 2x BW loss).
    // MLP comes from pair-unroll over CONSECUTIVE float4 (64B/lane contiguous).
    const long nvec2 = (long)nrows * 4;   // 32 floats/row = 4 pairs of float4

    const float4* P[5] = { (const float4*)p3a, (const float4*)p3b, (const float4*)p3c,
                           (const float4*)p3d, (const float4*)p3e };
    const float4* Q[5] = { (const float4*)y3a, (const float4*)y3b, (const float4*)y3c,
                           (const float4*)y3d, (const float4*)y3e };

    #pragma unroll
    for (int e = 0; e < 5; ++e) {
        const float4* __restrict__ p4  = P[e];
        const float4* __restrict__ q4  = Q[e];
        const float*  __restrict__ lab = (e < 3) ? l2yCC : l2yURW;
        const int w   = (e < 3) ? 3 : 2;
        const int col = (e < 3) ? e : e - 3;
        const int br  = (e < 3) ? 0 : 1;

        for (long u = tid; u < nvec2; u += T) {
            const long v   = u << 1;
            const long row = u >> 2;          // 4 float4-pairs per row

            // 4 independent contiguous payload loads, unconditional
            float4 pa = p4[v], pb = p4[v + 1];
            float4 qa = q4[v], qb = q4[v + 1];

            // inline mask (small L2-resident label arrays, multiplier semantics)
            float a = l1y[row * 2 + br];
            float c = lab[row * w + col];
            const float m = (a > 0.5f && c != 0.f) ? 1.f : 0.f;

            s3 += (double)(m * (bce4(pa, qa) + bce4(pb, qb)));
        }
    }

    // ---------- block reduction: 7 doubles -> global atomics ----------
    double vals[7] = { s1, s2cc, s2urw, s3, nCC, nURW, n3 };
    __shared__ double sm[4][7];
    const int lane = threadIdx.x & 63;
    const int wid  = threadIdx.x >> 6;

    #pragma unroll
    for (int j = 0; j < 7; ++j) {
        double x = vals[j];
        #pragma unroll
        for (int o = 32; o > 0; o >>= 1)
            x += __shfl_down(x, o, 64);
        if (lane == 0) sm[wid][j] = x;
    }
    __syncthreads();

    if (threadIdx.x == 0) {
        #pragma unroll
        for (int j = 0; j < 7; ++j)
            atomicAdd(&acc[j], sm[0][j] + sm[1][j] + sm[2][j] + sm[3][j]);

        // last-block finalize (device-scope atomics; G16-safe)
        __threadfence();
        if (atomicAdd(done, 1u) == gridDim.x - 1) {
            double S1   = atomicAdd(&acc[0], 0.0);
            double S2cc = atomicAdd(&acc[1], 0.0);
            double S2u  = atomicAdd(&acc[2], 0.0);
            double S3   = atomicAdd(&acc[3], 0.0);
            double NCC  = atomicAdd(&acc[4], 0.0);
            double NU   = atomicAdd(&acc[5], 0.0);
            double N3   = atomicAdd(&acc[6], 0.0);

            double level1 = S1 / ((double)nrows * 2.0);
            double l2 = 0.0;
            if (NCC > 0.0) l2 += S2cc / (NCC * 3.0);
            if (NU  > 0.0) l2 += S2u  / (NU  * 2.0);
            double level2 = 0.5 * l2;
            double level3 = (N3 > 0.0) ? (S3 / 32.0) / N3 : 0.0;

            out[0] = (float)(level1 + level2 + level3);
        }
    }
}

extern "C" void kernel_launch(void* const* d_in, const int* in_sizes, int n_in,
                              void* d_out, int out_size, void* d_ws, size_t ws_size,
                              hipStream_t stream) {
    const float* l1p   = (const float*)d_in[0];
    const float* l2pCC = (const float*)d_in[1];
    const float* l2pURW= (const float*)d_in[2];
    const float* p3a   = (const float*)d_in[3];
    const float* p3b   = (const float*)d_in[4];
    const float* p3c   = (const float*)d_in[5];
    const float* p3d   = (const float*)d_in[6];
    const float* p3e   = (const float*)d_in[7];
    const float* l1y   = (const float*)d_in[8];
    const float* l2yCC = (const float*)d_in[9];
    const float* l2yURW= (const float*)d_in[10];
    const float* y3a   = (const float*)d_in[11];
    const float* y3b   = (const float*)d_in[12];
    const float* y3c   = (const float*)d_in[13];
    const float* y3d   = (const float*)d_in[14];
    const float* y3e   = (const float*)d_in[15];

    const int nrows = in_sizes[0] / 2;

    double*       acc  = (double*)d_ws;
    unsigned int* done = (unsigned int*)((char*)d_ws + 56);

    hipMemsetAsync(d_ws, 0, 64, stream);

    hml_fused<<<NBLK, TPB, 0, stream>>>(
        l1p, l2pCC, l2pURW, p3a, p3b, p3c, p3d, p3e,
        l1y, l2yCC, l2yURW, y3a, y3b, y3c, y3d, y3e,
        nrows, acc, done, (float*)d_out);
}

// Round 7
// 166.048 us; speedup vs baseline: 1.4783x; 1.4783x over previous
//
#include <hip/hip_runtime.h>

#define TPB 256

// y is exactly 0.0f or 1.0f; -(y*log(p) + (1-y)*log1p(-p)) reduces to a select.
__device__ __forceinline__ float bce1(float p, float y) {
    return (y > 0.5f) ? -__logf(p) : -__logf(1.0f - p);
}
__device__ __forceinline__ float bce4(float4 p, float4 y) {
    return bce1(p.x, y.x) + bce1(p.y, y.y) + bce1(p.z, y.z) + bce1(p.w, y.w);
}

template<int N>
__device__ __forceinline__ void block_reduce_atomic(const double* vals, double* acc) {
    __shared__ double sm[4][N];
    const int lane = threadIdx.x & 63;
    const int wid  = threadIdx.x >> 6;
    #pragma unroll
    for (int j = 0; j < N; ++j) {
        double v = vals[j];
        #pragma unroll
        for (int o = 32; o > 0; o >>= 1)
            v += __shfl_down(v, o, 64);
        if (lane == 0) sm[wid][j] = v;
    }
    __syncthreads();
    if (threadIdx.x == 0) {
        #pragma unroll
        for (int j = 0; j < N; ++j)
            atomicAdd(&acc[j], sm[0][j] + sm[1][j] + sm[2][j] + sm[3][j]);
    }
}

__device__ __forceinline__ const float4* sel5(unsigned e,
    const float4* a, const float4* b, const float4* c,
    const float4* d, const float4* f) {
    const float4* r = a;
    r = (e == 1u) ? b : r;
    r = (e == 2u) ? c : r;
    r = (e == 3u) ? d : r;
    r = (e == 4u) ? f : r;
    return r;
}

// ================= compaction path =================

// Kernel A: level1+level2 sums AND compacted active (row,entry) item list.
__global__ void __launch_bounds__(TPB) hml_l1l2_compact(
    const float* __restrict__ l1p, const float* __restrict__ l2pCC,
    const float* __restrict__ l2pURW, const float* __restrict__ l1y,
    const float* __restrict__ l2yCC, const float* __restrict__ l2yURW,
    int nrows, double* __restrict__ acc,
    unsigned* __restrict__ gcount, unsigned* __restrict__ gitems)
{
    __shared__ unsigned lcnt, lbase;
    __shared__ unsigned litems[TPB * 5];

    double s1 = 0, s2cc = 0, s2urw = 0, nCC = 0, nURW = 0;
    const long T = (long)gridDim.x * blockDim.x;

    for (long i0 = (long)blockIdx.x * blockDim.x; i0 < nrows; i0 += T) {
        const long i = i0 + threadIdx.x;
        const bool valid = (i < nrows);

        unsigned myitems[5];
        int mycnt = 0;

        if (valid) {
            float2 p1 = ((const float2*)l1p)[i];
            float2 y1 = ((const float2*)l1y)[i];
            float2 pu = ((const float2*)l2pURW)[i];
            float2 yu = ((const float2*)l2yURW)[i];
            float c0p = l2pCC[i*3+0], c1p = l2pCC[i*3+1], c2p = l2pCC[i*3+2];
            float c0y = l2yCC[i*3+0], c1y = l2yCC[i*3+1], c2y = l2yCC[i*3+2];

            s1 += (double)(bce1(p1.x, y1.x) + bce1(p1.y, y1.y));

            const bool aCC  = (y1.x > 0.5f);
            const bool aURW = (y1.y > 0.5f);
            const float fCC  = aCC  ? 1.f : 0.f;
            const float fURW = aURW ? 1.f : 0.f;

            s2cc  += (double)(fCC  * (bce1(c0p, c0y) + bce1(c1p, c1y) + bce1(c2p, c2y)));
            s2urw += (double)(fURW * (bce1(pu.x, yu.x) + bce1(pu.y, yu.y)));
            nCC   += (double)fCC;
            nURW  += (double)fURW;

            const unsigned rw = ((unsigned)i) << 3;
            if (aCC  && c0y  != 0.f) myitems[mycnt++] = rw | 0u;
            if (aCC  && c1y  != 0.f) myitems[mycnt++] = rw | 1u;
            if (aCC  && c2y  != 0.f) myitems[mycnt++] = rw | 2u;
            if (aURW && yu.x != 0.f) myitems[mycnt++] = rw | 3u;
            if (aURW && yu.y != 0.f) myitems[mycnt++] = rw | 4u;
        }

        // block-level compaction (uniform control flow: nrows assumed %TPB-friendly,
        // guarded by `valid` so syncs are uniform regardless)
        if (threadIdx.x == 0) lcnt = 0;
        __syncthreads();
        unsigned off = 0;
        if (mycnt > 0) off = atomicAdd(&lcnt, (unsigned)mycnt);
        for (int k = 0; k < mycnt; ++k) litems[off + k] = myitems[k];
        __syncthreads();
        if (threadIdx.x == 0) lbase = atomicAdd(gcount, lcnt);
        __syncthreads();
        for (unsigned j = threadIdx.x; j < lcnt; j += blockDim.x)
            gitems[lbase + j] = litems[j];
        __syncthreads();
    }

    double vals[5] = { s1, s2cc, s2urw, nCC, nURW };
    block_reduce_atomic<5>(vals, acc);
}

// Kernel B: gather active rows only. 8-lane groups; 4 items per iteration.
__global__ void __launch_bounds__(TPB) hml_l3_gather(
    const float* __restrict__ p3a, const float* __restrict__ p3b,
    const float* __restrict__ p3c, const float* __restrict__ p3d,
    const float* __restrict__ p3e,
    const float* __restrict__ y3a, const float* __restrict__ y3b,
    const float* __restrict__ y3c, const float* __restrict__ y3d,
    const float* __restrict__ y3e,
    const unsigned* __restrict__ gcount, const unsigned* __restrict__ gitems,
    int nrows, double* __restrict__ acc, unsigned int* __restrict__ done,
    float* __restrict__ out)
{
    const float4* P0 = (const float4*)p3a; const float4* Q0 = (const float4*)y3a;
    const float4* P1 = (const float4*)p3b; const float4* Q1 = (const float4*)y3b;
    const float4* P2 = (const float4*)p3c; const float4* Q2 = (const float4*)y3c;
    const float4* P3 = (const float4*)p3d; const float4* Q3 = (const float4*)y3d;
    const float4* P4 = (const float4*)p3e; const float4* Q4 = (const float4*)y3e;

    const unsigned cnt   = *gcount;
    const unsigned g     = ((unsigned)(blockIdx.x * blockDim.x + threadIdx.x)) >> 3;
    const unsigned lane8 = threadIdx.x & 7u;
    const unsigned G     = ((unsigned)(gridDim.x * blockDim.x)) >> 3;

    double s3 = 0;

    for (unsigned base = g * 4u; base < cnt; base += 4u * G) {
        // one 16B load fetches 4 consecutive items (broadcast across the 8 lanes)
        const uint4 it = *(const uint4*)(gitems + base);

        const float m0 = 1.f;                               // base < cnt by loop cond
        const float m1 = (base + 1u < cnt) ? 1.f : 0.f;
        const float m2 = (base + 2u < cnt) ? 1.f : 0.f;
        const float m3 = (base + 3u < cnt) ? 1.f : 0.f;
        const unsigned w0 = it.x;
        const unsigned w1 = (base + 1u < cnt) ? it.y : 0u;  // clamp tail to row0/e0
        const unsigned w2 = (base + 2u < cnt) ? it.z : 0u;
        const unsigned w3 = (base + 3u < cnt) ? it.w : 0u;

        // element index of this lane's float4 within the (row) block:
        // (w>>3)*8 + lane8  ==  (w & ~7u) | lane8
        const unsigned v0 = (w0 & ~7u) | lane8;
        const unsigned v1 = (w1 & ~7u) | lane8;
        const unsigned v2 = (w2 & ~7u) | lane8;
        const unsigned v3 = (w3 & ~7u) | lane8;

        const float4* pp0 = sel5(w0 & 7u, P0, P1, P2, P3, P4);
        const float4* qq0 = sel5(w0 & 7u, Q0, Q1, Q2, Q3, Q4);
        const float4* pp1 = sel5(w1 & 7u, P0, P1, P2, P3, P4);
        const float4* qq1 = sel5(w1 & 7u, Q0, Q1, Q2, Q3, Q4);
        const float4* pp2 = sel5(w2 & 7u, P0, P1, P2, P3, P4);
        const float4* qq2 = sel5(w2 & 7u, Q0, Q1, Q2, Q3, Q4);
        const float4* pp3 = sel5(w3 & 7u, P0, P1, P2, P3, P4);
        const float4* qq3 = sel5(w3 & 7u, Q0, Q1, Q2, Q3, Q4);

        // 8 unconditional independent 16B loads (each item = dense 128B chunk)
        float4 pA = pp0[v0], qA = qq0[v0];
        float4 pB = pp1[v1], qB = qq1[v1];
        float4 pC = pp2[v2], qC = qq2[v2];
        float4 pD = pp3[v3], qD = qq3[v3];

        s3 += (double)(m0 * bce4(pA, qA) + m1 * bce4(pB, qB)
                     + m2 * bce4(pC, qC) + m3 * bce4(pD, qD));
    }

    double vals[1] = { s3 };
    block_reduce_atomic<1>(vals, acc + 5);

    if (threadIdx.x == 0) {
        __threadfence();
        if (atomicAdd(done, 1u) == gridDim.x - 1) {
            double S1   = atomicAdd(&acc[0], 0.0);
            double S2cc = atomicAdd(&acc[1], 0.0);
            double S2u  = atomicAdd(&acc[2], 0.0);
            double NCC  = atomicAdd(&acc[3], 0.0);
            double NU   = atomicAdd(&acc[4], 0.0);
            double S3   = atomicAdd(&acc[5], 0.0);
            double N3   = (double)cnt;

            double level1 = S1 / ((double)nrows * 2.0);
            double l2 = 0.0;
            if (NCC > 0.0) l2 += S2cc / (NCC * 3.0);
            if (NU  > 0.0) l2 += S2u  / (NU  * 2.0);
            double level2 = 0.5 * l2;
            double level3 = (N3 > 0.0) ? (S3 / 32.0) / N3 : 0.0;

            out[0] = (float)(level1 + level2 + level3);
        }
    }
}

// ================= fallback path (round-3 replica, ws too small) =================

__global__ void __launch_bounds__(TPB) hml_l1l2_mask(
    const float* __restrict__ l1p, const float* __restrict__ l2pCC,
    const float* __restrict__ l2pURW, const float* __restrict__ l1y,
    const float* __restrict__ l2yCC, const float* __restrict__ l2yURW,
    int nrows, double* __restrict__ acc, unsigned char* __restrict__ mask)
{
    double s1 = 0, s2cc = 0, s2urw = 0, nCC = 0, nURW = 0, n3 = 0;
    const int tid = blockIdx.x * blockDim.x + threadIdx.x;
    const int T   = gridDim.x * blockDim.x;

    for (int i = tid; i < nrows; i += T) {
        float2 p1 = ((const float2*)l1p)[i];
        float2 y1 = ((const float2*)l1y)[i];
        float2 pu = ((const float2*)l2pURW)[i];
        float2 yu = ((const float2*)l2yURW)[i];
        float c0p = l2pCC[i*3+0], c1p = l2pCC[i*3+1], c2p = l2pCC[i*3+2];
        float c0y = l2yCC[i*3+0], c1y = l2yCC[i*3+1], c2y = l2yCC[i*3+2];

        s1 += (double)(bce1(p1.x, y1.x) + bce1(p1.y, y1.y));

        const bool aCC  = (y1.x > 0.5f);
        const bool aURW = (y1.y > 0.5f);
        const float fCC  = aCC  ? 1.f : 0.f;
        const float fURW = aURW ? 1.f : 0.f;

        s2cc  += (double)(fCC  * (bce1(c0p, c0y) + bce1(c1p, c1y) + bce1(c2p, c2y)));
        s2urw += (double)(fURW * (bce1(pu.x, yu.x) + bce1(pu.y, yu.y)));
        nCC  += (double)fCC;
        nURW += (double)fURW;

        const unsigned b0 = (aCC  && c0y  != 0.f) ? 1u : 0u;
        const unsigned b1 = (aCC  && c1y  != 0.f) ? 1u : 0u;
        const unsigned b2 = (aCC  && c2y  != 0.f) ? 1u : 0u;
        const unsigned b3 = (aURW && yu.x != 0.f) ? 1u : 0u;
        const unsigned b4 = (aURW && yu.y != 0.f) ? 1u : 0u;
        n3 += (double)(b0 + b1 + b2 + b3 + b4);
        mask[i] = (unsigned char)(b0 | (b1 << 1) | (b2 << 2) | (b3 << 3) | (b4 << 4));
    }

    double vals[6] = { s1, s2cc, s2urw, nCC, nURW, n3 };
    block_reduce_atomic<6>(vals, acc);
}

__global__ void __launch_bounds__(TPB) hml_l3_mask(
    const float* __restrict__ p3a, const float* __restrict__ p3b,
    const float* __restrict__ p3c, const float* __restrict__ p3d,
    const float* __restrict__ p3e,
    const float* __restrict__ y3a, const float* __restrict__ y3b,
    const float* __restrict__ y3c, const float* __restrict__ y3d,
    const float* __restrict__ y3e,
    const unsigned char* __restrict__ mask,
    int nrows, double* __restrict__ acc, unsigned int* __restrict__ done,
    float* __restrict__ out)
{
    double s3 = 0;
    const int tid = blockIdx.x * blockDim.x + threadIdx.x;
    const int T   = gridDim.x * blockDim.x;
    const int nvec = nrows * 8;

    const float4* P[5] = { (const float4*)p3a, (const float4*)p3b, (const float4*)p3c,
                           (const float4*)p3d, (const float4*)p3e };
    const float4* Q[5] = { (const float4*)y3a, (const float4*)y3b, (const float4*)y3c,
                           (const float4*)y3d, (const float4*)y3e };

    #pragma unroll
    for (int e = 0; e < 5; ++e) {
        const float4* p4 = P[e];
        const float4* q4 = Q[e];
        for (int v = tid; v < nvec; v += T) {
            const int row = v >> 3;
            float mf = (float)((mask[row] >> e) & 1);
            float4 p = p4[v];
            float4 q = q4[v];
            s3 += (double)(mf * bce4(p, q));
        }
    }

    double vals[1] = { s3 };
    block_reduce_atomic<1>(vals, acc + 6);

    if (threadIdx.x == 0) {
        __threadfence();
        if (atomicAdd(done, 1u) == gridDim.x - 1) {
            double S1   = atomicAdd(&acc[0], 0.0);
            double S2cc = atomicAdd(&acc[1], 0.0);
            double S2u  = atomicAdd(&acc[2], 0.0);
            double NCC  = atomicAdd(&acc[3], 0.0);
            double NU   = atomicAdd(&acc[4], 0.0);
            double N3   = atomicAdd(&acc[5], 0.0);
            double S3   = atomicAdd(&acc[6], 0.0);

            double level1 = S1 / ((double)nrows * 2.0);
            double l2 = 0.0;
            if (NCC > 0.0) l2 += S2cc / (NCC * 3.0);
            if (NU  > 0.0) l2 += S2u  / (NU  * 2.0);
            double level2 = 0.5 * l2;
            double level3 = (N3 > 0.0) ? (S3 / 32.0) / N3 : 0.0;

            out[0] = (float)(level1 + level2 + level3);
        }
    }
}

extern "C" void kernel_launch(void* const* d_in, const int* in_sizes, int n_in,
                              void* d_out, int out_size, void* d_ws, size_t ws_size,
                              hipStream_t stream) {
    const float* l1p   = (const float*)d_in[0];
    const float* l2pCC = (const float*)d_in[1];
    const float* l2pURW= (const float*)d_in[2];
    const float* p3a   = (const float*)d_in[3];
    const float* p3b   = (const float*)d_in[4];
    const float* p3c   = (const float*)d_in[5];
    const float* p3d   = (const float*)d_in[6];
    const float* p3e   = (const float*)d_in[7];
    const float* l1y   = (const float*)d_in[8];
    const float* l2yCC = (const float*)d_in[9];
    const float* l2yURW= (const float*)d_in[10];
    const float* y3a   = (const float*)d_in[11];
    const float* y3b   = (const float*)d_in[12];
    const float* y3c   = (const float*)d_in[13];
    const float* y3d   = (const float*)d_in[14];
    const float* y3e   = (const float*)d_in[15];

    const int nrows = in_sizes[0] / 2;

    // ws layout: [0,56) acc doubles | [56,60) done | [60,64) count | [64,...) items/mask
    double*       acc   = (double*)d_ws;
    unsigned int* done  = (unsigned int*)((char*)d_ws + 56);
    unsigned int* count = (unsigned int*)((char*)d_ws + 60);

    hipMemsetAsync(d_ws, 0, 64, stream);

    const size_t need_items = 64 + (size_t)nrows * 5 * sizeof(unsigned) + 16;

    if (ws_size >= need_items) {
        unsigned* items = (unsigned*)((char*)d_ws + 64);
        const int gridA = (nrows + TPB - 1) / TPB;   // 1024: one row per thread
        hml_l1l2_compact<<<gridA, TPB, 0, stream>>>(
            l1p, l2pCC, l2pURW, l1y, l2yCC, l2yURW, nrows, acc, count, items);
        hml_l3_gather<<<2048, TPB, 0, stream>>>(
            p3a, p3b, p3c, p3d, p3e, y3a, y3b, y3c, y3d, y3e,
            count, items, nrows, acc, done, (float*)d_out);
    } else {
        unsigned char* mask = (unsigned char*)d_ws + 64;
        hml_l1l2_mask<<<1024, TPB, 0, stream>>>(
            l1p, l2pCC, l2pURW, l1y, l2yCC, l2yURW, nrows, acc, mask);
        hml_l3_mask<<<2048, TPB, 0, stream>>>(
            p3a, p3b, p3c, p3d, p3e, y3a, y3b, y3c, y3d, y3e,
            mask, nrows, acc, done, (float*)d_out);
    }
}

// Round 8
// 76.198 us; speedup vs baseline: 3.2215x; 2.1792x over previous
//
#include <hip/hip_runtime.h>

#define TPB 256
#define ROWS_PER_B 128   // B-kernel: one block = 128 rows, fully static schedule

// y is exactly 0.0f or 1.0f; -(y*log(p) + (1-y)*log1p(-p)) reduces to a select.
__device__ __forceinline__ float bce1(float p, float y) {
    return (y > 0.5f) ? -__logf(p) : -__logf(1.0f - p);
}
__device__ __forceinline__ float bce4(float4 p, float4 y) {
    return bce1(p.x, y.x) + bce1(p.y, y.y) + bce1(p.z, y.z) + bce1(p.w, y.w);
}

// block-reduce N doubles (shuffle + LDS), thread0 plain-stores to slot[j]
template<int N>
__device__ __forceinline__ void block_reduce_store(const double* vals, double* slot) {
    __shared__ double sm[4][N];
    const int lane = threadIdx.x & 63;
    const int wid  = threadIdx.x >> 6;
    #pragma unroll
    for (int j = 0; j < N; ++j) {
        double v = vals[j];
        #pragma unroll
        for (int o = 32; o > 0; o >>= 1)
            v += __shfl_down(v, o, 64);
        if (lane == 0) sm[wid][j] = v;
    }
    __syncthreads();
    if (threadIdx.x == 0) {
        #pragma unroll
        for (int j = 0; j < N; ++j)
            slot[j] = sm[0][j] + sm[1][j] + sm[2][j] + sm[3][j];
    }
}

// ---- kernel A: level1+level2 sums, per-row 5-bit mask byte, partials to slots ----
__global__ void __launch_bounds__(TPB) hml_A(
    const float* __restrict__ l1p, const float* __restrict__ l2pCC,
    const float* __restrict__ l2pURW, const float* __restrict__ l1y,
    const float* __restrict__ l2yCC, const float* __restrict__ l2yURW,
    int nrows, double* __restrict__ pA, unsigned char* __restrict__ mask)
{
    double s1 = 0, s2cc = 0, s2urw = 0, nCC = 0, nURW = 0, n3 = 0;
    const long i = (long)blockIdx.x * blockDim.x + threadIdx.x;   // one row per thread

    if (i < nrows) {
        float2 p1 = ((const float2*)l1p)[i];
        float2 y1 = ((const float2*)l1y)[i];
        float2 pu = ((const float2*)l2pURW)[i];
        float2 yu = ((const float2*)l2yURW)[i];
        float c0p = l2pCC[i*3+0], c1p = l2pCC[i*3+1], c2p = l2pCC[i*3+2];
        float c0y = l2yCC[i*3+0], c1y = l2yCC[i*3+1], c2y = l2yCC[i*3+2];

        s1 = (double)(bce1(p1.x, y1.x) + bce1(p1.y, y1.y));

        const bool aCC  = (y1.x > 0.5f);
        const bool aURW = (y1.y > 0.5f);
        const float fCC  = aCC  ? 1.f : 0.f;
        const float fURW = aURW ? 1.f : 0.f;

        s2cc  = (double)(fCC  * (bce1(c0p, c0y) + bce1(c1p, c1y) + bce1(c2p, c2y)));
        s2urw = (double)(fURW * (bce1(pu.x, yu.x) + bce1(pu.y, yu.y)));
        nCC   = (double)fCC;
        nURW  = (double)fURW;

        const unsigned b0 = (aCC  && c0y  != 0.f) ? 1u : 0u;
        const unsigned b1 = (aCC  && c1y  != 0.f) ? 1u : 0u;
        const unsigned b2 = (aCC  && c2y  != 0.f) ? 1u : 0u;
        const unsigned b3 = (aURW && yu.x != 0.f) ? 1u : 0u;
        const unsigned b4 = (aURW && yu.y != 0.f) ? 1u : 0u;
        n3 = (double)(b0 + b1 + b2 + b3 + b4);
        mask[i] = (unsigned char)(b0 | (b1 << 1) | (b2 << 2) | (b3 << 3) | (b4 << 4));
    }

    double vals[6] = { s1, s2cc, s2urw, nCC, nURW, n3 };
    block_reduce_store<6>(vals, pA + (size_t)blockIdx.x * 8);
}

// ---- kernel B: level3 — contiguous chunk per block, FULLY STATIC schedule ----
// Block c owns rows [c*128, c*128+128). Thread t: row = c*128 + (t>>1),
// half = t&1 -> float4 indices row*8 + half*4 + {0..3}. A wave's 64 lanes
// cover 32 rows x 128B = 4KB contiguous per load slot. Per entry: 8
// unconditional dwordx4 loads with compile-time offsets — no loops, no guards.
__global__ void __launch_bounds__(TPB) hml_B(
    const float* __restrict__ p3a, const float* __restrict__ p3b,
    const float* __restrict__ p3c, const float* __restrict__ p3d,
    const float* __restrict__ p3e,
    const float* __restrict__ y3a, const float* __restrict__ y3b,
    const float* __restrict__ y3c, const float* __restrict__ y3d,
    const float* __restrict__ y3e,
    const unsigned char* __restrict__ mask,
    int nrows, double* __restrict__ pB)
{
    const int  row  = blockIdx.x * ROWS_PER_B + (threadIdx.x >> 1);
    const int  half = threadIdx.x & 1;
    const long base = (long)row * 8 + half * 4;     // float4 index

    double s3 = 0;

    if (row < nrows) {
        const unsigned mb = mask[row];

        const float4* P[5] = { (const float4*)p3a, (const float4*)p3b, (const float4*)p3c,
                               (const float4*)p3d, (const float4*)p3e };
        const float4* Q[5] = { (const float4*)y3a, (const float4*)y3b, (const float4*)y3c,
                               (const float4*)y3d, (const float4*)y3e };

        #pragma unroll
        for (int e = 0; e < 5; ++e) {
            const float4* __restrict__ p4 = P[e] + base;
            const float4* __restrict__ q4 = Q[e] + base;

            // 8 independent unconditional 16B loads, static offsets
            float4 p0 = p4[0], p1 = p4[1], p2 = p4[2], p3 = p4[3];
            float4 q0 = q4[0], q1 = q4[1], q2 = q4[2], q3 = q4[3];

            const float mf = (float)((mb >> e) & 1u);
            s3 += (double)(mf * (bce4(p0, q0) + bce4(p1, q1)
                               + bce4(p2, q2) + bce4(p3, q3)));
        }
    }

    double vals[1] = { s3 };
    block_reduce_store<1>(vals, pB + blockIdx.x);
}

// ---- final: reduce partial slots, apply formula ----
__global__ void __launch_bounds__(TPB) hml_final(
    const double* __restrict__ pA, int nA,
    const double* __restrict__ pB, int nB,
    float* __restrict__ out, int nrows)
{
    double S[7] = { 0, 0, 0, 0, 0, 0, 0 };   // s1,s2cc,s2urw,nCC,nURW,n3,s3

    for (int i = threadIdx.x; i < nA; i += TPB) {
        #pragma unroll
        for (int j = 0; j < 6; ++j) S[j] += pA[(size_t)i * 8 + j];
    }
    for (int i = threadIdx.x; i < nB; i += TPB)
        S[6] += pB[i];

    __shared__ double sm[4][7];
    const int lane = threadIdx.x & 63;
    const int wid  = threadIdx.x >> 6;
    #pragma unroll
    for (int j = 0; j < 7; ++j) {
        double v = S[j];
        #pragma unroll
        for (int o = 32; o > 0; o >>= 1)
            v += __shfl_down(v, o, 64);
        if (lane == 0) sm[wid][j] = v;
    }
    __syncthreads();

    if (threadIdx.x == 0) {
        double s1   = sm[0][0] + sm[1][0] + sm[2][0] + sm[3][0];
        double s2cc = sm[0][1] + sm[1][1] + sm[2][1] + sm[3][1];
        double s2u  = sm[0][2] + sm[1][2] + sm[2][2] + sm[3][2];
        double nCC  = sm[0][3] + sm[1][3] + sm[2][3] + sm[3][3];
        double nU   = sm[0][4] + sm[1][4] + sm[2][4] + sm[3][4];
        double n3   = sm[0][5] + sm[1][5] + sm[2][5] + sm[3][5];
        double s3   = sm[0][6] + sm[1][6] + sm[2][6] + sm[3][6];

        double level1 = s1 / ((double)nrows * 2.0);
        double l2 = 0.0;
        if (nCC > 0.0) l2 += s2cc / (nCC * 3.0);
        if (nU  > 0.0) l2 += s2u  / (nU  * 2.0);
        double level2 = 0.5 * l2;
        double level3 = (n3 > 0.0) ? (s3 / 32.0) / n3 : 0.0;

        out[0] = (float)(level1 + level2 + level3);
    }
}

extern "C" void kernel_launch(void* const* d_in, const int* in_sizes, int n_in,
                              void* d_out, int out_size, void* d_ws, size_t ws_size,
                              hipStream_t stream) {
    const float* l1p   = (const float*)d_in[0];
    const float* l2pCC = (const float*)d_in[1];
    const float* l2pURW= (const float*)d_in[2];
    const float* p3a   = (const float*)d_in[3];
    const float* p3b   = (const float*)d_in[4];
    const float* p3c   = (const float*)d_in[5];
    const float* p3d   = (const float*)d_in[6];
    const float* p3e   = (const float*)d_in[7];
    const float* l1y   = (const float*)d_in[8];
    const float* l2yCC = (const float*)d_in[9];
    const float* l2yURW= (const float*)d_in[10];
    const float* y3a   = (const float*)d_in[11];
    const float* y3b   = (const float*)d_in[12];
    const float* y3c   = (const float*)d_in[13];
    const float* y3d   = (const float*)d_in[14];
    const float* y3e   = (const float*)d_in[15];

    const int nrows = in_sizes[0] / 2;

    const int nA = (nrows + TPB - 1) / TPB;            // 1024
    const int nB = (nrows + ROWS_PER_B - 1) / ROWS_PER_B;  // 2048

    // ws layout (all plain-stored every call — no memset needed):
    // pA: nA*8 doubles | pB: nB doubles | mask: nrows bytes
    double*        pA   = (double*)d_ws;
    double*        pB   = (double*)((char*)d_ws + (size_t)nA * 8 * sizeof(double));
    unsigned char* mask = (unsigned char*)((char*)pB + (size_t)nB * sizeof(double));

    hml_A<<<nA, TPB, 0, stream>>>(
        l1p, l2pCC, l2pURW, l1y, l2yCC, l2yURW, nrows, pA, mask);

    hml_B<<<nB, TPB, 0, stream>>>(
        p3a, p3b, p3c, p3d, p3e, y3a, y3b, y3c, y3d, y3e,
        mask, nrows, pB);

    hml_final<<<1, TPB, 0, stream>>>(pA, nA, pB, nB, (float*)d_out, nrows);
}